// Round 3
// baseline (669.891 us; speedup 1.0000x reference)
//
#include <hip/hip_runtime.h>
#include <hip/hip_bf16.h>
#include <cstdint>
#include <cstddef>

#define B_SZ 32768
#define H_SZ 896
#define K_SZ 2000
#define KPAD 2048
#define NPTR_COLS 256
#define NCAT 2304   /* KPAD + NPTR_COLS */
#define BM 256
#define BN 256
#define BK 32
#define NKS (H_SZ / BK)   /* 28 K-steps */
#define NT_ARG 8          /* n-tiles 0..7 are argmin tiles; tile 8 is ptr */

typedef float floatx4 __attribute__((ext_vector_type(4)));
typedef __bf16 bf16x8 __attribute__((ext_vector_type(8)));

// Masked-logit sentinel: must stay FINITE after bf16 RNE rounding (harness
// compares through bf16; -3.4e38 rounds to -inf there and produced nan).
#define MASK_NEG 1.0e30f

__device__ inline unsigned short f2bf_rne(float x) {
  unsigned u = __builtin_bit_cast(unsigned, x);
  unsigned r = u + 0x7fffu + ((u >> 16) & 1u);
  return (unsigned short)(r >> 16);
}
__device__ inline float bf2f(unsigned short b) {
  unsigned u = ((unsigned)b) << 16;
  return __builtin_bit_cast(float, u);
}

typedef __attribute__((address_space(1))) void GV;
typedef __attribute__((address_space(3))) void LV;
__device__ inline void load_lds16(const void* gsrc, void* ldst) {
  __builtin_amdgcn_global_load_lds((GV*)gsrc, (LV*)ldst, 16, 0, 0);
}

// ---------------------------------------------------------------------------
// Kernel 1 (fused): blocks [0, NCAT) build cat_hi/cat_lo bf16 split of
// [emb(2000); zeros(48); W(256)] rows x 896 plus normE[k]; blocks >= NCAT
// convert z -> zhi/zlo planes (8 floats per thread). Same hi/lo math
// everywhere => bit-identical MFMA inputs vs the verified kernel.
// ---------------------------------------------------------------------------
__global__ __launch_bounds__(256) void convert_all(
    const float* __restrict__ emb, const float* __restrict__ W,
    const float* __restrict__ z,
    unsigned short* __restrict__ cat_hi, unsigned short* __restrict__ cat_lo,
    float* __restrict__ normE,
    unsigned short* __restrict__ zhi, unsigned short* __restrict__ zlo) {
  const int bid = blockIdx.x;
  const int tid = threadIdx.x;
  if (bid < NCAT) {
    const int row = bid;
    const float* src = nullptr;
    bool zero = false;
    if (row < K_SZ)       src = emb + (size_t)row * H_SZ;
    else if (row < KPAD)  zero = true;
    else                  src = W + (size_t)(row - KPAD) * H_SZ;

    float ss = 0.f;
    for (int c = tid; c < H_SZ; c += 256) {
      float x = zero ? 0.f : src[c];
      unsigned short hb = f2bf_rne(x);
      float hf = bf2f(hb);
      unsigned short lb = f2bf_rne(x - hf);
      cat_hi[(size_t)row * H_SZ + c] = hb;
      cat_lo[(size_t)row * H_SZ + c] = lb;
      ss += x * x;
    }
    #pragma unroll
    for (int off = 32; off > 0; off >>= 1) ss += __shfl_down(ss, off);
    __shared__ float wsum[4];
    const int wave = tid >> 6, lane = tid & 63;
    if (lane == 0) wsum[wave] = ss;
    __syncthreads();
    if (tid == 0 && row < KPAD) normE[row] = wsum[0] + wsum[1] + wsum[2] + wsum[3];
  } else {
    const size_t t = (size_t)(bid - NCAT) * 256 + tid;
    const float* src = z + t * 8;
    float x[8];
    *(float4*)&x[0] = *(const float4*)src;
    *(float4*)&x[4] = *(const float4*)(src + 4);
    unsigned hv[4], lv[4];
    #pragma unroll
    for (int q = 0; q < 4; ++q) {
      unsigned short h0 = f2bf_rne(x[2 * q]), h1 = f2bf_rne(x[2 * q + 1]);
      float r0 = x[2 * q] - bf2f(h0), r1 = x[2 * q + 1] - bf2f(h1);
      unsigned short l0 = f2bf_rne(r0), l1 = f2bf_rne(r1);
      hv[q] = (unsigned)h0 | ((unsigned)h1 << 16);
      lv[q] = (unsigned)l0 | ((unsigned)l1 << 16);
    }
    *(uint4*)(zhi + t * 8) = make_uint4(hv[0], hv[1], hv[2], hv[3]);
    *(uint4*)(zlo + t * 8) = make_uint4(lv[0], lv[1], lv[2], lv[3]);
  }
}

// ---------------------------------------------------------------------------
// Kernel 2: 256x256-tile fused GEMM, FUSED-PHASE K-step. grid = (B/256, 9).
//   n-tile 0..7: cat cols nt*256.. -> per-row argmin partial nt
//   n-tile 8   : ptr logits (+bias, prompt-len mask)
// s = z . cat_row as bf16x3 (hi*hi + hi*lo + lo*hi), fp32 acc (per-acc
// product order identical to the verified kernel => bit-identical).
// dist proxy v = normE[k] - 2*s.
//
// Schedule: ONE barrier per K-step. All ds_reads of buf[cur] are issued in
// burst-consumption order (A-half1 + all B up front; A-half2 after burst 1)
// and the compiler inserts counted lgkmcnt waits before each MFMA burst
// (m97-verified behavior), so LDS reads overlap the MFMA pipe. The 8 DMA
// loads for buf[nxt] are issued at the top of the K-step and drained by one
// vmcnt(0) AFTER ~3100 cycles of MFMA cover, then s_barrier publishes
// buf[nxt] and licenses overwrite of buf[cur]. sched_barrier(0) pins the
// loop tail (no cross-iteration ds_read hoist past the barrier).
//
// LDS slot swizzle (both-sides, proven 0-conflict): logical 16B slot s of
// row r lives at phys slot s ^ ((r>>1)&3); DMA writes linearly so the
// lane's GLOBAL source fetches logical slot (lane&3)^((lane>>3)&3);
// ds_read applies the same XOR (csw).
// ---------------------------------------------------------------------------
__global__ __launch_bounds__(512, 2) void main_gemm(
    const unsigned short* __restrict__ zhi,
    const unsigned short* __restrict__ zlo,
    const unsigned short* __restrict__ cat_hi,
    const unsigned short* __restrict__ cat_lo,
    const float* __restrict__ normE,
    const float* __restrict__ bias,
    const int* __restrict__ plen_p,
    float* __restrict__ pmin, int* __restrict__ pidx,
    float* __restrict__ out_logits) {
  // 2 bufs x 2 planes x 256x32 ushort = 64 KB each for A and B -> 128 KB
  __shared__ unsigned short ldsA[2][2][BM * BK];
  __shared__ unsigned short ldsB[2][2][BN * BK];
  __shared__ float red_v[4][BM];
  __shared__ int   red_i[4][BM];

  const int tid = threadIdx.x;
  const int wave = tid >> 6, lane = tid & 63;
  const int wm = wave >> 2, wn = wave & 3;     // 2 x 4 wave grid; wave out 128x64
  const int m0 = blockIdx.x * BM;
  const int nt = blockIdx.y;
  const int n0 = nt * BN;
  const int lrow = lane & 15, lk = lane >> 4;
  const int csw = ((lk ^ ((lrow >> 1) & 3)) << 3);   // swizzled k-offset (shorts)

  // staging lane map: lane -> row seg*16+(lane>>2), phys slot lane&3;
  // source fetches logical slot (lane&3)^((lane>>3)&3)
  const int srow = lane >> 2;
  const int scol = (((lane & 3) ^ ((lane >> 3) & 3)) << 3);  // shorts

  // global source offsets (shorts) for this wave's two 16-row segments/array
  size_t offA[2], offB[2];
  #pragma unroll
  for (int s = 0; s < 2; ++s) {
    const int seg = wave * 2 + s;            // 0..15
    offA[s] = (size_t)(m0 + seg * 16 + srow) * H_SZ + scol;
    offB[s] = (size_t)(n0 + seg * 16 + srow) * H_SZ + scol;
  }

  auto STAGE = [&](int b, int s, int kk) {
    const int seg = wave * 2 + s;
    load_lds16(zhi    + offA[s] + kk, &ldsA[b][0][seg * 512]);
    load_lds16(zlo    + offA[s] + kk, &ldsA[b][1][seg * 512]);
    load_lds16(cat_hi + offB[s] + kk, &ldsB[b][0][seg * 512]);
    load_lds16(cat_lo + offB[s] + kk, &ldsB[b][1][seg * 512]);
  };

  floatx4 acc[8][4];
  #pragma unroll
  for (int i = 0; i < 8; ++i)
    #pragma unroll
    for (int j = 0; j < 4; ++j) acc[i][j] = (floatx4){0.f, 0.f, 0.f, 0.f};

  // prologue: stage K-step 0 into buf0, drain, sync
  STAGE(0, 0, 0);
  STAGE(0, 1, 0);
  asm volatile("s_waitcnt vmcnt(0)" ::: "memory");
  __builtin_amdgcn_s_barrier();

  for (int ks = 0; ks < NKS; ++ks) {
    const int cur = ks & 1, nxt = cur ^ 1;
    const int kk1 = (ks + 1) * BK;
    const bool pf = (ks + 1 < NKS);

    bf16x8 a1h[4], a1l[4], a2h[4], a2l[4], bh[4], bl[4];

    // ---- issue reads: A half1 (mi 0..3) + all B (nj 0..3) ----
    #pragma unroll
    for (int i = 0; i < 4; ++i) {
      const int r = (wm * 128 + i * 16 + lrow) * BK + csw;
      a1h[i] = *(const bf16x8*)&ldsA[cur][0][r];
      a1l[i] = *(const bf16x8*)&ldsA[cur][1][r];
    }
    #pragma unroll
    for (int j = 0; j < 4; ++j) {
      const int r = (wn * 64 + j * 16 + lrow) * BK + csw;
      bh[j] = *(const bf16x8*)&ldsB[cur][0][r];
      bl[j] = *(const bf16x8*)&ldsB[cur][1][r];
    }
    // ---- issue next-K-step DMA early: drained after full MFMA cover ----
    if (pf) { STAGE(nxt, 0, kk1); STAGE(nxt, 1, kk1); }

    __builtin_amdgcn_s_setprio(1);
    // ---- burst 1: mi 0-3 x nj 0-1 (needs a1, b0/b1) ----
    #pragma unroll
    for (int i = 0; i < 4; ++i)
      #pragma unroll
      for (int j = 0; j < 2; ++j) {
        floatx4 c = acc[i][j];
        c = __builtin_amdgcn_mfma_f32_16x16x32_bf16(a1h[i], bh[j], c, 0, 0, 0);
        c = __builtin_amdgcn_mfma_f32_16x16x32_bf16(a1h[i], bl[j], c, 0, 0, 0);
        c = __builtin_amdgcn_mfma_f32_16x16x32_bf16(a1l[i], bh[j], c, 0, 0, 0);
        acc[i][j] = c;
      }
    // ---- issue A half2 reads (cover under bursts 1-2) ----
    #pragma unroll
    for (int i = 0; i < 4; ++i) {
      const int r = (wm * 128 + (4 + i) * 16 + lrow) * BK + csw;
      a2h[i] = *(const bf16x8*)&ldsA[cur][0][r];
      a2l[i] = *(const bf16x8*)&ldsA[cur][1][r];
    }
    // ---- burst 2: mi 0-3 x nj 2-3 ----
    #pragma unroll
    for (int i = 0; i < 4; ++i)
      #pragma unroll
      for (int j = 0; j < 2; ++j) {
        floatx4 c = acc[i][2 + j];
        c = __builtin_amdgcn_mfma_f32_16x16x32_bf16(a1h[i], bh[2 + j], c, 0, 0, 0);
        c = __builtin_amdgcn_mfma_f32_16x16x32_bf16(a1h[i], bl[2 + j], c, 0, 0, 0);
        c = __builtin_amdgcn_mfma_f32_16x16x32_bf16(a1l[i], bh[2 + j], c, 0, 0, 0);
        acc[i][2 + j] = c;
      }
    // ---- burst 3: mi 4-7 x nj 2-3 ----
    #pragma unroll
    for (int i = 0; i < 4; ++i)
      #pragma unroll
      for (int j = 0; j < 2; ++j) {
        floatx4 c = acc[4 + i][2 + j];
        c = __builtin_amdgcn_mfma_f32_16x16x32_bf16(a2h[i], bh[2 + j], c, 0, 0, 0);
        c = __builtin_amdgcn_mfma_f32_16x16x32_bf16(a2h[i], bl[2 + j], c, 0, 0, 0);
        c = __builtin_amdgcn_mfma_f32_16x16x32_bf16(a2l[i], bh[2 + j], c, 0, 0, 0);
        acc[4 + i][2 + j] = c;
      }
    // ---- burst 4: mi 4-7 x nj 0-1 ----
    #pragma unroll
    for (int i = 0; i < 4; ++i)
      #pragma unroll
      for (int j = 0; j < 2; ++j) {
        floatx4 c = acc[4 + i][j];
        c = __builtin_amdgcn_mfma_f32_16x16x32_bf16(a2h[i], bh[j], c, 0, 0, 0);
        c = __builtin_amdgcn_mfma_f32_16x16x32_bf16(a2h[i], bl[j], c, 0, 0, 0);
        c = __builtin_amdgcn_mfma_f32_16x16x32_bf16(a2l[i], bh[j], c, 0, 0, 0);
        acc[4 + i][j] = c;
      }
    __builtin_amdgcn_s_setprio(0);

    // ---- drain own DMA (covered by ~3100 cyc of MFMA), publish, pin ----
    if (pf) { asm volatile("s_waitcnt vmcnt(0)" ::: "memory"); }
    __builtin_amdgcn_s_barrier();
    __builtin_amdgcn_sched_barrier(0);
  }

  // ------------------------------ epilogue ------------------------------
  if (nt < NT_ARG) {
    float nE[4]; bool valid[4]; int kcol[4];
    #pragma unroll
    for (int nj = 0; nj < 4; ++nj) {
      kcol[nj] = n0 + wn * 64 + nj * 16 + lrow;
      valid[nj] = (kcol[nj] < K_SZ);
      nE[nj] = normE[kcol[nj]];
    }
    #pragma unroll
    for (int mi = 0; mi < 8; ++mi) {
      #pragma unroll
      for (int r = 0; r < 4; ++r) {
        float v = 3.4e38f; int id = kcol[0];
        #pragma unroll
        for (int nj = 0; nj < 4; ++nj) {
          const float vv = valid[nj] ? (nE[nj] - 2.0f * acc[mi][nj][r]) : 3.4e38f;
          if (vv < v) { v = vv; id = kcol[nj]; }   // nj ascending => lowest k on ties
        }
        #pragma unroll
        for (int m = 1; m < 16; m <<= 1) {
          const float ov = __shfl_xor(v, m);
          const int   oid = __shfl_xor(id, m);
          if (ov < v || (ov == v && oid < id)) { v = ov; id = oid; }
        }
        if (lrow == 0) {
          const int row_local = wm * 128 + mi * 16 + lk * 4 + r;
          red_v[wn][row_local] = v;
          red_i[wn][row_local] = id;
        }
      }
    }
    __syncthreads();
    if (tid < BM) {
      float v = red_v[0][tid]; int id = red_i[0][tid];
      #pragma unroll
      for (int w = 1; w < 4; ++w) {        // wn ascending = k ascending; strict <
        const float vw = red_v[w][tid];
        if (vw < v) { v = vw; id = red_i[w][tid]; }
      }
      pmin[(size_t)nt * B_SZ + m0 + tid] = v;
      pidx[(size_t)nt * B_SZ + m0 + tid] = id;
    }
  } else {
    const int plen = *plen_p;
    #pragma unroll
    for (int nj = 0; nj < 4; ++nj) {
      const int c = wn * 64 + nj * 16 + lrow;       // 0..255
      const float bv = bias[c];
      const bool masked = ((c & 127) >= plen);
      #pragma unroll
      for (int mi = 0; mi < 8; ++mi) {
        const int growbase = m0 + wm * 128 + mi * 16 + lk * 4;
        #pragma unroll
        for (int r = 0; r < 4; ++r) {
          // Sentinel must stay finite in bf16 (see MASK_NEG note).
          const float val = masked ? -MASK_NEG : (acc[mi][nj][r] + bv);
          out_logits[(size_t)(growbase + r) * NPTR_COLS + c] = val;
        }
      }
    }
  }
}

// ---------------------------------------------------------------------------
// Kernel 3: merge 8 K-split partials, gather emb[idx], op_state = z + (e - z)
// ---------------------------------------------------------------------------
__global__ __launch_bounds__(256) void merge_gather(
    const float* __restrict__ z, const float* __restrict__ emb,
    const float* __restrict__ pmin, const int* __restrict__ pidx,
    float* __restrict__ out0) {
  const int row = blockIdx.x;
  float v = pmin[row];
  int  id = pidx[row];
  #pragma unroll
  for (int t = 1; t < NT_ARG; ++t) {       // ascending k-ranges; strict <
    const float vt = pmin[(size_t)t * B_SZ + row];
    if (vt < v) { v = vt; id = pidx[(size_t)t * B_SZ + row]; }
  }
  const float4* e4 = (const float4*)(emb + (size_t)id * H_SZ);
  const float4* z4 = (const float4*)(z + (size_t)row * H_SZ);
  float4* o4 = (float4*)(out0 + (size_t)row * H_SZ);
  const int t = threadIdx.x;
  if (t < H_SZ / 4) {  // 224
    const float4 zz = z4[t], ee = e4[t];
    float4 r;
    r.x = zz.x + (ee.x - zz.x);
    r.y = zz.y + (ee.y - zz.y);
    r.z = zz.z + (ee.z - zz.z);
    r.w = zz.w + (ee.w - zz.w);
    o4[t] = r;
  }
}

extern "C" void kernel_launch(void* const* d_in, const int* in_sizes, int n_in,
                              void* d_out, int out_size, void* d_ws, size_t ws_size,
                              hipStream_t stream) {
  const float* z    = (const float*)d_in[0];
  const float* emb  = (const float*)d_in[1];
  const float* W    = (const float*)d_in[2];
  const float* bias = (const float*)d_in[3];
  const int*   plen = (const int*)d_in[4];
  float* out = (float*)d_out;

  char* ws = (char*)d_ws;
  // cat_hi: 2304*896*2 = 4,128,768 B ; cat_lo same ; normE 8 KB ; 8-way partials
  unsigned short* cat_hi = (unsigned short*)(ws);
  unsigned short* cat_lo = (unsigned short*)(ws + 4128768);
  float* normE = (float*)(ws + 8257536);
  float* pmin  = (float*)(ws + 8265728);   // 8 * 32768 * 4 = 1,048,576 B
  int*   pidx  = (int*)(ws + 9314304);     // 8 * 32768 * 4 = 1,048,576 B

  // z hi/lo bf16 planes staged IN THE OUTPUT BUFFER's op_state region
  // (exactly B*H*4 bytes). main_gemm consumes them fully before merge_gather
  // overwrites the region with op_state (stream order guarantees this).
  unsigned short* zhi = (unsigned short*)out;
  unsigned short* zlo = zhi + (size_t)B_SZ * H_SZ;
  float* out_logits = out + (size_t)B_SZ * H_SZ;   // second output, [B,2,128]

  // fused conversion: 2304 cat blocks + 14336 z blocks (32768*896/2048)
  convert_all<<<dim3(NCAT + B_SZ * H_SZ / 2048), dim3(256), 0, stream>>>(
      emb, W, z, cat_hi, cat_lo, normE, zhi, zlo);
  main_gemm<<<dim3(B_SZ / BM, 9), dim3(512), 0, stream>>>(
      zhi, zlo, cat_hi, cat_lo, normE, bias, plen, pmin, pidx, out_logits);
  merge_gather<<<dim3(B_SZ), dim3(256), 0, stream>>>(z, emb, pmin, pidx, out);
}